// Round 1
// baseline (639.234 us; speedup 1.0000x reference)
//
#include <hip/hip_runtime.h>

typedef _Float16 f16;
typedef _Float16 f16x8 __attribute__((ext_vector_type(8)));
typedef float f32x4 __attribute__((ext_vector_type(4)));

#define MFMA16(a, b, c) __builtin_amdgcn_mfma_f32_16x16x32_f16((a), (b), (c), 0, 0, 0)
#define LOG2E 1.44269504088896340736f

// N=16384, IN=256, OUT=128
#define NROWS 16384
#define INDIM 256
#define ODIM 128

// ---------------------------------------------------------------------------
// Kernel 0: transpose W [256][128] fp32 -> WT [128][256] fp16
// ---------------------------------------------------------------------------
__global__ void prep_kernel(const float* __restrict__ Wq, const float* __restrict__ Wk,
                            const float* __restrict__ Wv,
                            f16* __restrict__ WqT, f16* __restrict__ WkT, f16* __restrict__ WvT) {
    int w = blockIdx.x;
    const float* W = (w == 0) ? Wq : ((w == 1) ? Wk : Wv);
    f16* WT = (w == 0) ? WqT : ((w == 1) ? WkT : WvT);
    for (int j = threadIdx.x; j < INDIM * ODIM; j += 256) {
        int n = j >> 8;      // 0..127  (output row of WT)
        int k = j & 255;     // 0..255
        WT[j] = (f16)W[k * ODIM + n];
    }
}

// ---------------------------------------------------------------------------
// Kernel 1: projections.
// blocks 0..255  : Q,K   -> Qh,Kh fp16 [16384][128] row-major
// blocks 256..511: V^T   -> Vt    fp16 [128][16384] row-major
// block=256 thr, wave handles 16 rows (Q/K) or 16 cols (V).
// MFMA 16x16x32 f16: A[m=lane&15][k=quad*8+j], B[k=quad*8+j][n=lane&15],
// C/D: col=lane&15, row=quad*4+reg  (HW-verified mappings).
// ---------------------------------------------------------------------------
__global__ __launch_bounds__(256) void proj_kernel(
    const float* __restrict__ x,
    const f16* __restrict__ WqT, const f16* __restrict__ WkT, const f16* __restrict__ WvT,
    const float* __restrict__ bq, const float* __restrict__ bk, const float* __restrict__ bv,
    f16* __restrict__ Qh, f16* __restrict__ Kh, f16* __restrict__ Vt) {
    int blk = blockIdx.x;
    int wave = threadIdx.x >> 6;
    int lane = threadIdx.x & 63;
    int l16 = lane & 15, quad = lane >> 4;

    if (blk < 256) {
        int r0 = blk * 64 + wave * 16;
        // A-fragments from x (fp32 -> fp16)
        f16x8 ax[8];
        const float* xp = x + (size_t)(r0 + l16) * INDIM + quad * 8;
#pragma unroll
        for (int kc = 0; kc < 8; kc++) {
            f32x4 u = *(const f32x4*)(xp + kc * 32);
            f32x4 v = *(const f32x4*)(xp + kc * 32 + 4);
            f16x8 t;
            t[0] = (f16)u[0]; t[1] = (f16)u[1]; t[2] = (f16)u[2]; t[3] = (f16)u[3];
            t[4] = (f16)v[0]; t[5] = (f16)v[1]; t[6] = (f16)v[2]; t[7] = (f16)v[3];
            ax[kc] = t;
        }
#pragma unroll
        for (int nt = 0; nt < 8; nt++) {
            f32x4 aq = {0.f, 0.f, 0.f, 0.f}, ak = {0.f, 0.f, 0.f, 0.f};
            const f16* wq = WqT + (nt * 16 + l16) * INDIM + quad * 8;
            const f16* wk = WkT + (nt * 16 + l16) * INDIM + quad * 8;
#pragma unroll
            for (int kc = 0; kc < 8; kc++) {
                f16x8 bqf = *(const f16x8*)(wq + kc * 32);
                f16x8 bkf = *(const f16x8*)(wk + kc * 32);
                aq = MFMA16(ax[kc], bqf, aq);
                ak = MFMA16(ax[kc], bkf, ak);
            }
            int col = nt * 16 + l16;
            float biasq = bq[col], biask = bk[col];
#pragma unroll
            for (int r = 0; r < 4; r++) {
                int row = r0 + quad * 4 + r;
                Qh[(size_t)row * ODIM + col] = (f16)(aq[r] + biasq);
                Kh[(size_t)row * ODIM + col] = (f16)(ak[r] + biask);
            }
        }
    } else {
        int i0 = (blk - 256) * 64 + wave * 16;
        // B-fragments from x (n = i = lane&15, k contiguous)
        f16x8 bx[8];
        const float* xp = x + (size_t)(i0 + l16) * INDIM + quad * 8;
#pragma unroll
        for (int kc = 0; kc < 8; kc++) {
            f32x4 u = *(const f32x4*)(xp + kc * 32);
            f32x4 v = *(const f32x4*)(xp + kc * 32 + 4);
            f16x8 t;
            t[0] = (f16)u[0]; t[1] = (f16)u[1]; t[2] = (f16)u[2]; t[3] = (f16)u[3];
            t[4] = (f16)v[0]; t[5] = (f16)v[1]; t[6] = (f16)v[2]; t[7] = (f16)v[3];
            bx[kc] = t;
        }
#pragma unroll
        for (int dt = 0; dt < 8; dt++) {
            f32x4 acc = {0.f, 0.f, 0.f, 0.f};
            const f16* wv = WvT + (dt * 16 + l16) * INDIM + quad * 8;
#pragma unroll
            for (int kc = 0; kc < 8; kc++) {
                f16x8 a = *(const f16x8*)(wv + kc * 32);
                acc = MFMA16(a, bx[kc], acc);
            }
#pragma unroll
            for (int r = 0; r < 4; r++) {
                int d = dt * 16 + quad * 4 + r;
                Vt[(size_t)d * NROWS + i0 + l16] = (f16)(acc[r] + bv[d]);
            }
        }
    }
}

// ---------------------------------------------------------------------------
// Kernel 2: flash attention, unscaled softmax(Q K^T) V.
// grid = 128 q-tiles * nsplit.  block = 256 thr = 4 waves, wave owns 32 rows
// (2 row-tiles of 16).  BN = 128 per iteration.  Online softmax per row.
// ---------------------------------------------------------------------------
__global__ __launch_bounds__(256, 2) void flash_kernel(
    const f16* __restrict__ Qh, const f16* __restrict__ Kh, const f16* __restrict__ Vt,
    float* __restrict__ Opart, float* __restrict__ ml, float* __restrict__ Out,
    int nsplit, int niter) {
    int blk = blockIdx.x;
    int qt = blk / nsplit;
    int sp = blk % nsplit;
    int wave = threadIdx.x >> 6;
    int lane = threadIdx.x & 63;
    int l16 = lane & 15, quad = lane >> 4;

    __shared__ __align__(16) f16 Plds[4][32][136];   // per-wave P tile, +8 pad

    int rowbase = qt * 128 + wave * 32;

    // Q fragments (row-tiles rt=0,1; k-chunks kc=0..3)
    f16x8 qf[2][4];
#pragma unroll
    for (int rt = 0; rt < 2; rt++) {
        const f16* qp = Qh + (size_t)(rowbase + rt * 16 + l16) * ODIM + quad * 8;
#pragma unroll
        for (int kc = 0; kc < 4; kc++) qf[rt][kc] = *(const f16x8*)(qp + kc * 32);
    }

    f32x4 o[2][8];
#pragma unroll
    for (int rt = 0; rt < 2; rt++)
#pragma unroll
        for (int dt = 0; dt < 8; dt++) o[rt][dt] = (f32x4){0.f, 0.f, 0.f, 0.f};
    float m_r[2][4], l_r[2][4];
#pragma unroll
    for (int rt = 0; rt < 2; rt++)
#pragma unroll
        for (int r = 0; r < 4; r++) { m_r[rt][r] = -__builtin_inff(); l_r[rt][r] = 0.f; }

    int j0 = sp * (niter * 128);
    for (int it = 0; it < niter; ++it, j0 += 128) {
        // ---- scores S = Q K^T  (16x128 per row-tile)
        f32x4 s[2][8];
#pragma unroll
        for (int ct = 0; ct < 8; ct++) {
            const f16* kp = Kh + (size_t)(j0 + ct * 16 + l16) * ODIM + quad * 8;
            f32x4 a0 = {0.f, 0.f, 0.f, 0.f}, a1 = {0.f, 0.f, 0.f, 0.f};
#pragma unroll
            for (int kc = 0; kc < 4; kc++) {
                f16x8 kf = *(const f16x8*)(kp + kc * 32);
                a0 = MFMA16(qf[0][kc], kf, a0);
                a1 = MFMA16(qf[1][kc], kf, a1);
            }
            s[0][ct] = a0;
            s[1][ct] = a1;
        }
        // ---- online softmax per row-tile
#pragma unroll
        for (int rt = 0; rt < 2; rt++) {
            float mx[4];
#pragma unroll
            for (int r = 0; r < 4; r++) {
                float v = s[rt][0][r];
#pragma unroll
                for (int ct = 1; ct < 8; ct++) v = fmaxf(v, s[rt][ct][r]);
                mx[r] = v;
            }
#pragma unroll
            for (int d = 1; d < 16; d <<= 1)
#pragma unroll
                for (int r = 0; r < 4; r++) mx[r] = fmaxf(mx[r], __shfl_xor(mx[r], d, 64));
            float alpha[4];
#pragma unroll
            for (int r = 0; r < 4; r++) {
                float mn = fmaxf(m_r[rt][r], mx[r]);
                alpha[r] = __builtin_amdgcn_exp2f((m_r[rt][r] - mn) * LOG2E);
                m_r[rt][r] = mn;
            }
            float rs[4];
#pragma unroll
            for (int r = 0; r < 4; r++) {
                float c = -m_r[rt][r] * LOG2E;
                float sum = 0.f;
#pragma unroll
                for (int ct = 0; ct < 8; ct++) {
                    float p = __builtin_amdgcn_exp2f(s[rt][ct][r] * LOG2E + c);
                    s[rt][ct][r] = p;
                    sum += p;
                }
                rs[r] = sum;
            }
#pragma unroll
            for (int d = 1; d < 16; d <<= 1)
#pragma unroll
                for (int r = 0; r < 4; r++) rs[r] += __shfl_xor(rs[r], d, 64);
#pragma unroll
            for (int r = 0; r < 4; r++) l_r[rt][r] = l_r[rt][r] * alpha[r] + rs[r];
#pragma unroll
            for (int dt = 0; dt < 8; dt++)
#pragma unroll
                for (int r = 0; r < 4; r++) o[rt][dt][r] *= alpha[r];
            // P (C/D layout) -> LDS row-major [32][136]
#pragma unroll
            for (int ct = 0; ct < 8; ct++)
#pragma unroll
                for (int r = 0; r < 4; r++)
                    Plds[wave][rt * 16 + quad * 4 + r][ct * 16 + l16] = (f16)s[rt][ct][r];
        }
        // ---- P A-fragments from LDS (wave-private; in-wave LDS order is safe)
        f16x8 pf[2][4];
#pragma unroll
        for (int rt = 0; rt < 2; rt++)
#pragma unroll
            for (int kc = 0; kc < 4; kc++)
                pf[rt][kc] = *(const f16x8*)&Plds[wave][rt * 16 + l16][kc * 32 + quad * 8];
        // ---- O += P V
#pragma unroll
        for (int dt = 0; dt < 8; dt++) {
            const f16* vp = Vt + (size_t)(dt * 16 + l16) * NROWS + j0 + quad * 8;
#pragma unroll
            for (int kc = 0; kc < 4; kc++) {
                f16x8 vf = *(const f16x8*)(vp + kc * 32);
                o[0][dt] = MFMA16(pf[0][kc], vf, o[0][dt]);
                o[1][dt] = MFMA16(pf[1][kc], vf, o[1][dt]);
            }
        }
    }

    if (nsplit == 1) {
#pragma unroll
        for (int rt = 0; rt < 2; rt++) {
            float inv[4];
#pragma unroll
            for (int r = 0; r < 4; r++) inv[r] = 1.f / l_r[rt][r];
#pragma unroll
            for (int dt = 0; dt < 8; dt++)
#pragma unroll
                for (int r = 0; r < 4; r++)
                    Out[(size_t)(rowbase + rt * 16 + quad * 4 + r) * ODIM + dt * 16 + l16] =
                        o[rt][dt][r] * inv[r];
        }
    } else {
        float* op = Opart + ((size_t)sp * NROWS + rowbase) * ODIM;
#pragma unroll
        for (int rt = 0; rt < 2; rt++)
#pragma unroll
            for (int dt = 0; dt < 8; dt++)
#pragma unroll
                for (int r = 0; r < 4; r++)
                    op[(rt * 16 + quad * 4 + r) * ODIM + dt * 16 + l16] = o[rt][dt][r];
        if (l16 == 0) {
            float* mlp = ml + ((size_t)sp * NROWS + rowbase) * 2;
#pragma unroll
            for (int rt = 0; rt < 2; rt++)
#pragma unroll
                for (int r = 0; r < 4; r++) {
                    mlp[(rt * 16 + quad * 4 + r) * 2 + 0] = m_r[rt][r];
                    mlp[(rt * 16 + quad * 4 + r) * 2 + 1] = l_r[rt][r];
                }
        }
    }
}

// ---------------------------------------------------------------------------
// Kernel 3: merge K-split partials (log-sum-exp weighted)
// ---------------------------------------------------------------------------
__global__ __launch_bounds__(256) void merge_kernel(const float* __restrict__ Opart,
                                                    const float* __restrict__ ml,
                                                    float* __restrict__ out, int nsplit) {
    int idx = blockIdx.x * 256 + threadIdx.x;   // 0 .. 16384*128-1
    int row = idx >> 7;
    float mv[4], lv[4];
    float M = -__builtin_inff();
    for (int s = 0; s < nsplit; s++) {
        mv[s] = ml[((size_t)s * NROWS + row) * 2 + 0];
        lv[s] = ml[((size_t)s * NROWS + row) * 2 + 1];
        M = fmaxf(M, mv[s]);
    }
    float acc = 0.f, den = 0.f;
    for (int s = 0; s < nsplit; s++) {
        float w = __builtin_amdgcn_exp2f((mv[s] - M) * LOG2E);
        den += w * lv[s];
        acc += w * Opart[(size_t)s * (NROWS * ODIM) + idx];
    }
    out[idx] = acc / den;
}

// ---------------------------------------------------------------------------
extern "C" void kernel_launch(void* const* d_in, const int* in_sizes, int n_in,
                              void* d_out, int out_size, void* d_ws, size_t ws_size,
                              hipStream_t stream) {
    const float* x  = (const float*)d_in[0];
    const float* Wq = (const float*)d_in[1];
    const float* bq = (const float*)d_in[2];
    const float* Wk = (const float*)d_in[3];
    const float* bk = (const float*)d_in[4];
    const float* Wv = (const float*)d_in[5];
    const float* bv = (const float*)d_in[6];
    float* out = (float*)d_out;
    char* ws = (char*)d_ws;

    const size_t WT_BYTES = (size_t)ODIM * INDIM * sizeof(f16);      // 64 KB
    const size_t QKV_BYTES = (size_t)NROWS * ODIM * sizeof(f16);     // 4 MB
    f16* WqT = (f16*)(ws);
    f16* WkT = (f16*)(ws + WT_BYTES);
    f16* WvT = (f16*)(ws + 2 * WT_BYTES);
    f16* Qh  = (f16*)(ws + 3 * WT_BYTES);
    f16* Kh  = (f16*)(ws + 3 * WT_BYTES + QKV_BYTES);
    f16* Vt  = (f16*)(ws + 3 * WT_BYTES + 2 * QKV_BYTES);
    size_t base = 3 * WT_BYTES + 3 * QKV_BYTES;                      // ~12.8 MB

    const size_t OPART_BYTES = (size_t)NROWS * ODIM * sizeof(float); // 8 MB
    const size_t ML_BYTES = (size_t)NROWS * 2 * sizeof(float);       // 128 KB

    int nsplit = 1;
    if (ws_size >= base + 4 * (OPART_BYTES + ML_BYTES)) nsplit = 4;
    else if (ws_size >= base + 2 * (OPART_BYTES + ML_BYTES)) nsplit = 2;

    float* Opart = (float*)(ws + base);
    float* ml    = (float*)(ws + base + (size_t)nsplit * OPART_BYTES);

    prep_kernel<<<3, 256, 0, stream>>>(Wq, Wk, Wv, WqT, WkT, WvT);
    proj_kernel<<<512, 256, 0, stream>>>(x, WqT, WkT, WvT, bq, bk, bv, Qh, Kh, Vt);
    flash_kernel<<<128 * nsplit, 256, 0, stream>>>(Qh, Kh, Vt, Opart, ml, out, nsplit,
                                                   128 / nsplit);
    if (nsplit > 1)
        merge_kernel<<<(NROWS * ODIM) / 256, 256, 0, stream>>>(Opart, ml, out, nsplit);
}